// Round 3
// baseline (329.305 us; speedup 1.0000x reference)
//
#include <hip/hip_runtime.h>
#include <stdint.h>

typedef unsigned short bfu;
typedef __attribute__((ext_vector_type(8))) short bf16x8;   // MFMA A/B frag
typedef __attribute__((ext_vector_type(4))) float f32x4;    // MFMA C/D frag

__device__ __forceinline__ bfu f2b(float f) {
  unsigned int i = __builtin_bit_cast(unsigned int, f);
  i += 0x7FFFu + ((i >> 16) & 1u);  // round-to-nearest-even
  return (bfu)(i >> 16);
}

// async global->LDS, 16B per lane. LDS dest must be wave-uniform base + lane*16.
__device__ __forceinline__ void stage16(const bfu* g, bfu* l) {
  __builtin_amdgcn_global_load_lds(
      (const __attribute__((address_space(1))) void*)g,
      (__attribute__((address_space(3))) void*)l, 16, 0, 0);
}

// ---------------------------------------------------------------------------
// C[M,N] = A[M,K] @ B[N,K]^T. 64x128 tile, BK=64.
// Prefetch double-buffered (one raw s_barrier + vmcnt(0) per K-step) with
// T2 XOR-swizzled LDS (both-sides involution: linear gload_lds dest,
// pre-swizzled global source col, swizzled ds_read col).
// 4 waves in 2x2: wave computes 32 rows x 64 cols (acc[2][4]).
// MODE 0: atomicAdd f32 (split-K via blockIdx.z when zIsK)
// MODE 1: store bf16 via LDS repack (swizzled, 16B/lane stores)
// MODE 2: store f32 with +bias[n]
template <int MODE>
__global__ __launch_bounds__(256) void gemm64p(
    const bfu* __restrict__ A, const bfu* __restrict__ B, void* __restrict__ Cv,
    const float* __restrict__ bias,
    int lda, int ldb, int ldc,
    long long sA, long long sB, long long sC,
    int Klen, int zIsK) {
  // two buffers of (At 64x64 = 4096) + (Bt 128x64 = 8192) = 12288 bfu (24KB)
  __shared__ __align__(16) bfu S[24576];
  const int tid = threadIdx.x;
  const int lane = tid & 63;
  const int wid = tid >> 6;
  const int l15 = lane & 15, l4 = lane >> 4;
  const int wm = wid >> 1, wn = wid & 1;

  int k0 = 0;
  long long cOff = 0;
  if (zIsK) {
    k0 = blockIdx.z * Klen;
  } else {
    A += (long long)blockIdx.z * sA;
    B += (long long)blockIdx.z * sB;
    cOff = (long long)blockIdx.z * sC;
  }
  const int m0 = blockIdx.y * 64;
  const int n0 = blockIdx.x * 128;
  const bfu* Ag = A + (long long)m0 * lda + k0;
  const bfu* Bg = B + (long long)n0 * ldb + k0;

  f32x4 acc[2][4];
  const f32x4 zero = {0.f, 0.f, 0.f, 0.f};
#pragma unroll
  for (int r = 0; r < 2; ++r)
#pragma unroll
    for (int c = 0; c < 4; ++c) acc[r][c] = zero;

  const int lrow = lane >> 3;              // 0..7 sub-row within 8-row group
  const int ldst = (lane & 7) * 8;         // linear LDS dest col (16B chunks)
  const int lsrc = ldst ^ (lrow * 8);      // pre-swizzled global source col
  const int ksw = (l15 & 7) * 8;           // swizzled ds_read col offset

  const int nIter = Klen >> 6;

  auto STAGE = [&](int kt, bfu* buf) {
    const bfu* Ak = Ag + kt * 64;
    const bfu* Bk = Bg + kt * 64;
#pragma unroll
    for (int j = 0; j < 2; ++j) {
      const int row = (wid * 2 + j) * 8 + lrow;
      stage16(Ak + (long long)row * lda + lsrc, buf + row * 64 + ldst);
    }
#pragma unroll
    for (int j = 0; j < 4; ++j) {
      const int row = (wid * 4 + j) * 8 + lrow;
      stage16(Bk + (long long)row * ldb + lsrc, buf + 4096 + row * 64 + ldst);
    }
  };

  STAGE(0, S);
  asm volatile("s_waitcnt vmcnt(0)" ::: "memory");
  __builtin_amdgcn_s_barrier();

  int cur = 0;
  for (int kt = 0; kt < nIter; ++kt) {
    bfu* bufc = S + (cur ? 12288 : 0);
    bfu* bufn = S + (cur ? 0 : 12288);
    if (kt + 1 < nIter) STAGE(kt + 1, bufn);
#pragma unroll
    for (int kk = 0; kk < 2; ++kk) {
      const int ko = (kk * 32 + l4 * 8) ^ ksw;
      bf16x8 af[2], bfr[4];
#pragma unroll
      for (int r = 0; r < 2; ++r)
        af[r] = *(const bf16x8*)(bufc + (wm * 32 + r * 16 + l15) * 64 + ko);
#pragma unroll
      for (int c = 0; c < 4; ++c)
        bfr[c] = *(const bf16x8*)(bufc + 4096 + (wn * 64 + c * 16 + l15) * 64 + ko);
#pragma unroll
      for (int r = 0; r < 2; ++r)
#pragma unroll
        for (int c = 0; c < 4; ++c)
          acc[r][c] = __builtin_amdgcn_mfma_f32_16x16x32_bf16(af[r], bfr[c], acc[r][c], 0, 0, 0);
    }
    asm volatile("s_waitcnt vmcnt(0)" ::: "memory");
    __builtin_amdgcn_s_barrier();
    cur ^= 1;
  }

  if (MODE == 0) {
    float* Cf = (float*)Cv;
#pragma unroll
    for (int r = 0; r < 2; ++r) {
#pragma unroll
      for (int c = 0; c < 4; ++c) {
        const int gr = m0 + wm * 32 + r * 16 + (l4 << 2);
        const int gc = n0 + wn * 64 + c * 16 + l15;
#pragma unroll
        for (int v = 0; v < 4; ++v)
          atomicAdd(Cf + cOff + (long long)(gr + v) * ldc + gc, acc[r][c][v]);
      }
    }
  } else if (MODE == 2) {
    float* Cf = (float*)Cv;
#pragma unroll
    for (int r = 0; r < 2; ++r) {
#pragma unroll
      for (int c = 0; c < 4; ++c) {
        const int gr = m0 + wm * 32 + r * 16 + (l4 << 2);
        const int gc = n0 + wn * 64 + c * 16 + l15;
        const float bval = bias[gc];
#pragma unroll
        for (int v = 0; v < 4; ++v)
          Cf[cOff + (long long)(gr + v) * ldc + gc] = acc[r][c][v] + bval;
      }
    }
  } else {
    // bf16 epilogue: repack 64x128 C tile via LDS (XOR-swizzled), 16B stores.
#pragma unroll
    for (int r = 0; r < 2; ++r) {
#pragma unroll
      for (int c = 0; c < 4; ++c) {
        const int col = wn * 64 + c * 16 + l15;
#pragma unroll
        for (int v = 0; v < 4; ++v) {
          const int row = wm * 32 + r * 16 + (l4 << 2) + v;
          S[row * 128 + (col ^ (((row >> 2) & 3) << 4))] = f2b(acc[r][c][v]);
        }
      }
    }
    __syncthreads();
    bfu* Cb = (bfu*)Cv;
#pragma unroll
    for (int i = 0; i < 4; ++i) {
      const int j = i * 256 + tid;      // 0..1023 uint4s
      const int row = j >> 4;           // 0..63
      const int colbase = (j & 15) * 8; // 0..120
      const int sc = colbase ^ (((row >> 2) & 3) << 4);
      uint4 val = *(const uint4*)(S + row * 128 + sc);
      *(uint4*)(Cb + cOff + (long long)(m0 + row) * ldc + n0 + colbase) = val;
    }
  }
}

// ---------------------------------------------------------------------------
// C[M,N] = A[M,K] @ B[N,K]^T. 128x128 tile, BK=64, prefetch + swizzle.
// PIPE=2: double-buffer (64KB LDS, 2 blocks/CU).
// PIPE=3: triple-buffer, counted vmcnt(16) — two load batches stay in flight
//         across barriers (T4); for 1-block/CU grids.
// 4 waves 2x2, wave computes 64x64 (acc[4][4] = 32 MFMA/K-step).
// MODE 1: store bf16 via LDS repack.  MODE 2: store f32 + bias[n].
template <int MODE, int PIPE>
__global__ __launch_bounds__(256) void gemm128p(
    const bfu* __restrict__ A, const bfu* __restrict__ B, void* __restrict__ Cv,
    const float* __restrict__ bias,
    int lda, int ldb, int ldc,
    long long sA, long long sB, long long sC,
    int Klen) {
  // per buffer: At 128x64 (8192) + Bt 128x64 (8192) = 16384 bfu (32KB)
  __shared__ __align__(16) bfu S[PIPE * 16384];
  const int tid = threadIdx.x;
  const int lane = tid & 63;
  const int wid = tid >> 6;
  const int l15 = lane & 15, l4 = lane >> 4;
  const int wm = wid >> 1, wn = wid & 1;

  A += (long long)blockIdx.z * sA;
  B += (long long)blockIdx.z * sB;
  const long long cOff = (long long)blockIdx.z * sC;
  const int m0 = blockIdx.y * 128;
  const int n0 = blockIdx.x * 128;
  const bfu* Ag = A + (long long)m0 * lda;
  const bfu* Bg = B + (long long)n0 * ldb;

  f32x4 acc[4][4];
  const f32x4 zero = {0.f, 0.f, 0.f, 0.f};
#pragma unroll
  for (int r = 0; r < 4; ++r)
#pragma unroll
    for (int c = 0; c < 4; ++c) acc[r][c] = zero;

  const int lrow = lane >> 3;
  const int ldst = (lane & 7) * 8;
  const int lsrc = ldst ^ (lrow * 8);
  const int ksw = (l15 & 7) * 8;

  const int nIter = Klen >> 6;

  auto STAGE = [&](int kt, bfu* buf) {
    const bfu* Ak = Ag + kt * 64;
    const bfu* Bk = Bg + kt * 64;
#pragma unroll
    for (int j = 0; j < 4; ++j) {
      const int row = (wid * 4 + j) * 8 + lrow;
      stage16(Ak + (long long)row * lda + lsrc, buf + row * 64 + ldst);
    }
#pragma unroll
    for (int j = 0; j < 4; ++j) {
      const int row = (wid * 4 + j) * 8 + lrow;
      stage16(Bk + (long long)row * ldb + lsrc, buf + 8192 + row * 64 + ldst);
    }
  };

  // prologue: fill first PIPE-1 buffers
  STAGE(0, S);
  if (PIPE == 3 && nIter > 1) STAGE(1, S + 16384);

  for (int kt = 0; kt < nIter; ++kt) {
    // post-compute barrier: all waves done reading the buffer that the next
    // STAGE will overwrite.
    if (kt > 0) __builtin_amdgcn_s_barrier();
    const int pf = kt + PIPE - 1;  // tile to prefetch
    if (pf < nIter) STAGE(pf, S + 16384 * (pf % PIPE));
    // counted wait: tile kt's 8 loads done; later batches stay in flight.
    const int rem = nIter - 1 - kt;
    if (PIPE == 3 && rem >= 2)
      asm volatile("s_waitcnt vmcnt(16)" ::: "memory");
    else if (rem >= 1)
      asm volatile("s_waitcnt vmcnt(8)" ::: "memory");
    else
      asm volatile("s_waitcnt vmcnt(0)" ::: "memory");
    __builtin_amdgcn_s_barrier();

    const bfu* bufc = S + 16384 * (kt % PIPE);
#pragma unroll
    for (int kk = 0; kk < 2; ++kk) {
      const int ko = (kk * 32 + l4 * 8) ^ ksw;
      bf16x8 af[4], bfr[4];
#pragma unroll
      for (int r = 0; r < 4; ++r)
        af[r] = *(const bf16x8*)(bufc + (wm * 64 + r * 16 + l15) * 64 + ko);
#pragma unroll
      for (int c = 0; c < 4; ++c)
        bfr[c] = *(const bf16x8*)(bufc + 8192 + (wn * 64 + c * 16 + l15) * 64 + ko);
#pragma unroll
      for (int r = 0; r < 4; ++r)
#pragma unroll
        for (int c = 0; c < 4; ++c)
          acc[r][c] = __builtin_amdgcn_mfma_f32_16x16x32_bf16(af[r], bfr[c], acc[r][c], 0, 0, 0);
    }
  }
  // trailing barrier: last tile's LDS reads done in all waves before epilogue
  // reuses S (MODE 1 repack).
  __builtin_amdgcn_s_barrier();

  if (MODE == 2) {
    float* Cf = (float*)Cv;
#pragma unroll
    for (int r = 0; r < 4; ++r) {
#pragma unroll
      for (int c = 0; c < 4; ++c) {
        const int gr = m0 + wm * 64 + r * 16 + (l4 << 2);
        const int gc = n0 + wn * 64 + c * 16 + l15;
        const float bval = bias[gc];
#pragma unroll
        for (int v = 0; v < 4; ++v)
          Cf[cOff + (long long)(gr + v) * ldc + gc] = acc[r][c][v] + bval;
      }
    }
  } else {
    // bf16 epilogue: repack 128x128 C tile via LDS (XOR-swizzled), 16B stores.
#pragma unroll
    for (int r = 0; r < 4; ++r) {
#pragma unroll
      for (int c = 0; c < 4; ++c) {
        const int col = wn * 64 + c * 16 + l15;
#pragma unroll
        for (int v = 0; v < 4; ++v) {
          const int row = wm * 64 + r * 16 + (l4 << 2) + v;
          S[row * 128 + (col ^ (((row >> 2) & 3) << 4))] = f2b(acc[r][c][v]);
        }
      }
    }
    __syncthreads();
    bfu* Cb = (bfu*)Cv;
#pragma unroll
    for (int i = 0; i < 8; ++i) {
      const int j = i * 256 + tid;      // 0..2047 uint4s
      const int row = j >> 4;           // 0..127
      const int colbase = (j & 15) * 8; // 0..120
      const int sc = colbase ^ (((row >> 2) & 3) << 4);
      uint4 val = *(const uint4*)(S + row * 128 + sc);
      *(uint4*)(Cb + cOff + (long long)(m0 + row) * ldc + n0 + colbase) = val;
    }
  }
}

// ---------------- helpers ----------------
// fused: Xb (bf16 copy) + XTb (bf16 transpose) from one read of X.
__global__ void convT_x(const float* __restrict__ in, bfu* __restrict__ outN,
                        bfu* __restrict__ outT, int R, int C) {
  __shared__ bfu t[32][33];
  const int c0 = blockIdx.x * 32, r0 = blockIdx.y * 32;
  const int tx = threadIdx.x, ty = threadIdx.y;
  for (int i = ty; i < 32; i += 8) {
    bfu b = f2b(in[(long long)(r0 + i) * C + (c0 + tx)]);
    outN[(long long)(r0 + i) * C + (c0 + tx)] = b;
    t[i][tx] = b;
  }
  __syncthreads();
  for (int i = ty; i < 32; i += 8)
    outT[(long long)(c0 + i) * R + (r0 + tx)] = t[tx][i];
}

__global__ void transpose_k(const float* __restrict__ in, bfu* __restrict__ out,
                            int R, int C) {
  __shared__ bfu t[32][33];
  const long long boff = (long long)blockIdx.z * R * C;
  const int c0 = blockIdx.x * 32, r0 = blockIdx.y * 32;
  const int tx = threadIdx.x, ty = threadIdx.y;
  for (int i = ty; i < 32; i += 8)
    t[i][tx] = f2b(in[boff + (long long)(r0 + i) * C + (c0 + tx)]);
  __syncthreads();
  for (int i = ty; i < 32; i += 8)
    out[boff + (long long)(c0 + i) * R + (r0 + tx)] = t[tx][i];
}

__global__ __launch_bounds__(256) void conv_mat(const float* __restrict__ src,
                                                bfu* __restrict__ dst, int count4) {
  int i = blockIdx.x * 256 + threadIdx.x;
  if (i < count4) {
    float4 f = ((const float4*)src)[i];
    ushort4 o;
    o.x = f2b(f.x); o.y = f2b(f.y); o.z = f2b(f.z); o.w = f2b(f.w);
    ((ushort4*)dst)[i] = o;
  }
}

__global__ __launch_bounds__(256) void zero_k(float* __restrict__ p) {
  p[blockIdx.x * 256 + threadIdx.x] = 0.f;
}

__global__ __launch_bounds__(256) void zero_out_k(float* __restrict__ p, int n) {
  int i = blockIdx.x * 256 + threadIdx.x;
  if (i < n) p[i] = 0.f;
}

__global__ __launch_bounds__(256) void cast_kv(const float* __restrict__ K32,
                                               const float* __restrict__ V32,
                                               bfu* __restrict__ Kb, bfu* __restrict__ VTb) {
  int idx = blockIdx.x * 256 + threadIdx.x;
  int a = idx >> 9, b = idx & 511;
  Kb[idx] = f2b(K32[idx]);
  VTb[idx] = f2b(V32[b * 512 + a]);
}

__global__ __launch_bounds__(256) void cvec_k(const float* __restrict__ K32,
                                              const float* __restrict__ bq,
                                              float* __restrict__ cb) {
  const int lane = threadIdx.x & 63;
  const int w = blockIdx.x * 4 + (threadIdx.x >> 6);
  const int h = w >> 9, a = w & 511;
  float s = 0.f;
#pragma unroll
  for (int i = 0; i < 8; ++i) {
    int q = i * 64 + lane;
    s += K32[a * 512 + q] * bq[h * 512 + q];
  }
#pragma unroll
  for (int off = 32; off; off >>= 1) s += __shfl_xor(s, off, 64);
  if (lane == 0) cb[w] = s;
}

// In-place softmax over Ecat[s][h*512 .. +512], wave per row.
__global__ __launch_bounds__(256) void softmax_k(bfu* __restrict__ E, const float* __restrict__ cb) {
  const int lane = threadIdx.x & 63;
  const int w = blockIdx.x * 4 + (threadIdx.x >> 6);
  const int h = w >> 13;
  const int s = w & 8191;
  bfu* row = E + (long long)s * 4096 + h * 512;
  const float* ch = cb + h * 512 + lane * 8;
  const float scale = 0.044194173824159216f;  // 1/sqrt(512)
  union { uint4 u; bfu us[8]; } io;
  io.u = *(const uint4*)(row + lane * 8);
  float v[8];
  float m = -1e30f;
#pragma unroll
  for (int j = 0; j < 8; ++j) {
    unsigned int bi = ((unsigned int)io.us[j]) << 16;
    v[j] = (__builtin_bit_cast(float, bi) + ch[j]) * scale;
    m = fmaxf(m, v[j]);
  }
#pragma unroll
  for (int off = 32; off; off >>= 1) m = fmaxf(m, __shfl_xor(m, off, 64));
  float sum = 0.f;
#pragma unroll
  for (int j = 0; j < 8; ++j) { v[j] = __expf(v[j] - m); sum += v[j]; }
#pragma unroll
  for (int off = 32; off; off >>= 1) sum += __shfl_xor(sum, off, 64);
  const float rinv = 1.0f / sum;
#pragma unroll
  for (int j = 0; j < 8; ++j) io.us[j] = f2b(v[j] * rinv);
  *(uint4*)(row + lane * 8) = io.u;
}

extern "C" void kernel_launch(void* const* d_in, const int* in_sizes, int n_in,
                              void* d_out, int out_size, void* d_ws, size_t ws_size,
                              hipStream_t stream) {
  (void)in_sizes; (void)n_in;
  const float* X    = (const float*)d_in[0];  // [8192,512]
  const float* enc0 = (const float*)d_in[1];  // [512,8192]
  const float* enc1 = (const float*)d_in[2];  // [512,8192]
  const float* Wq   = (const float*)d_in[3];  // [8,512,512]
  const float* bq   = (const float*)d_in[4];  // [8,512]
  const float* Wc   = (const float*)d_in[5];  // [512,4096]
  const float* bc   = (const float*)d_in[6];  // [512]
  float* out = (float*)d_out;                 // [8192,512] f32

  const size_t NEED = 83902464;  // 80.02 MB
  if (ws_size < NEED) {
    zero_out_k<<<dim3((out_size + 255) / 256), 256, 0, stream>>>(out, out_size);
    return;
  }
  char* w = (char*)d_ws;
  // Ecat (64 MB, written by logits GEMM) overlays all transients below it.
  bfu*   Ecat  = (bfu*)(w + 0);           // [8192][4096] 64 MB
  bfu*   XTb   = (bfu*)(w + 0);           // [512][8192]   8 MB (transient)
  bfu*   enc0b = (bfu*)(w + 8388608);     // [512][8192]   8 MB (transient)
  bfu*   enc1b = (bfu*)(w + 16777216);    // [512][8192]   8 MB (transient)
  bfu*   WqTb  = (bfu*)(w + 25165824);    // [8][512][512] 4 MB (transient)
  bfu*   Wcb   = (bfu*)(w + 29360128);    // [512][4096]   4 MB (transient)
  float* K32   = (float*)(w + 33554432);  // [512][512]    1 MB (transient)
  float* V32   = (float*)(w + 34603008);  // [512][512]    1 MB (transient)
  bfu*   Kb    = (bfu*)(w + 35651584);    // [512][512]  0.5 MB (transient)
  bfu*   VTb   = (bfu*)(w + 36175872);    // [512][512]  0.5 MB (transient)
  bfu*   Xb    = (bfu*)(w + 67108864);    // [8192][512]   8 MB
  bfu*   Mb    = (bfu*)(w + 75497472);    // [8][512][512] 4 MB
  bfu*   Ncat  = (bfu*)(w + 79691776);    // [512][4096]   4 MB
  float* cb    = (float*)(w + 83886080);  // [8][512]     16 KB

  conv_mat<<<dim3(4096), 256, 0, stream>>>(enc0, enc0b, 1048576);
  conv_mat<<<dim3(4096), 256, 0, stream>>>(enc1, enc1b, 1048576);
  conv_mat<<<dim3(2048), 256, 0, stream>>>(Wc, Wcb, 524288);

  dim3 tb(32, 8, 1);
  // fused X convert + transpose (one read of X)
  convT_x<<<dim3(16, 256, 1), tb, 0, stream>>>(X, Xb, XTb, 8192, 512);
  transpose_k<<<dim3(16, 16, 8), tb, 0, stream>>>(Wq, WqTb, 512, 512);

  zero_k<<<dim3(2048), 256, 0, stream>>>(K32);  // K32+V32 contiguous

  // K = enc0 @ X, V = enc1 @ X  (split-K over 16 chunks of 512; 512 blocks)
  gemm64p<0><<<dim3(4, 8, 16), 256, 0, stream>>>(enc0b, XTb, K32, nullptr,
      8192, 8192, 512, 0, 0, 0, 512, 1);
  gemm64p<0><<<dim3(4, 8, 16), 256, 0, stream>>>(enc1b, XTb, V32, nullptr,
      8192, 8192, 512, 0, 0, 0, 512, 1);
  cast_kv<<<dim3(1024), 256, 0, stream>>>(K32, V32, Kb, VTb);
  cvec_k<<<dim3(1024), 256, 0, stream>>>(K32, bq, cb);

  // M_h = K @ Wq_h
  gemm64p<1><<<dim3(4, 8, 8), 256, 0, stream>>>(Kb, WqTb, Mb, nullptr,
      512, 512, 512, 0, 262144, 262144, 512, 0);
  // N_h = Wc_h @ V -> Ncat[o][h*512+a]
  gemm64p<1><<<dim3(4, 8, 8), 256, 0, stream>>>(Wcb, VTb, Ncat, nullptr,
      4096, 512, 4096, 512, 0, 512, 512, 0);

  // logits_h = X @ M_h^T -> Ecat[s][h*512+a]  (128x128 tile, 2048 blocks, 2/CU)
  gemm128p<1, 2><<<dim3(4, 64, 8), 256, 0, stream>>>(Xb, Mb, Ecat, nullptr,
      512, 512, 4096, 0, 262144, 512, 512);
  softmax_k<<<dim3(16384), 256, 0, stream>>>(Ecat, cb);

  // out = Ecat @ Ncat^T + bc  (128x128 tile, 256 blocks, 3-deep counted vmcnt)
  gemm128p<2, 3><<<dim3(4, 64, 1), 256, 0, stream>>>(Ecat, Ncat, out, bc,
      4096, 4096, 512, 0, 0, 0, 4096);
}

// Round 4
// 300.372 us; speedup vs baseline: 1.0963x; 1.0963x over previous
//
#include <hip/hip_runtime.h>
#include <stdint.h>

typedef unsigned short bfu;
typedef __attribute__((ext_vector_type(8))) short bf16x8;   // MFMA A/B frag
typedef __attribute__((ext_vector_type(4))) float f32x4;    // MFMA C/D frag

__device__ __forceinline__ bfu f2b(float f) {
  unsigned int i = __builtin_bit_cast(unsigned int, f);
  i += 0x7FFFu + ((i >> 16) & 1u);  // round-to-nearest-even
  return (bfu)(i >> 16);
}

// async global->LDS, 16B per lane. LDS dest must be wave-uniform base + lane*16.
__device__ __forceinline__ void stage16(const bfu* g, bfu* l) {
  __builtin_amdgcn_global_load_lds(
      (const __attribute__((address_space(1))) void*)g,
      (__attribute__((address_space(3))) void*)l, 16, 0, 0);
}

// ---------------------------------------------------------------------------
// C[M,N] = A[M,K] @ B[N,K]^T. 64x128 tile, BK=64.
// Prefetch double-buffered (one raw s_barrier + vmcnt(0) per K-step) with
// T2 XOR-swizzled LDS. 4 waves 2x2: wave computes 32x64 (acc[2][4]).
// MODE 0: atomicAdd f32 (split-K via blockIdx.z when zIsK)
// MODE 1: store bf16 via LDS repack (swizzled, 16B/lane stores)
template <int MODE>
__global__ __launch_bounds__(256) void gemm64p(
    const bfu* __restrict__ A, const bfu* __restrict__ B, void* __restrict__ Cv,
    const float* __restrict__ bias,
    int lda, int ldb, int ldc,
    long long sA, long long sB, long long sC,
    int Klen, int zIsK) {
  // two buffers of (At 64x64 = 4096) + (Bt 128x64 = 8192) = 12288 bfu (24KB)
  __shared__ __align__(16) bfu S[24576];
  const int tid = threadIdx.x;
  const int lane = tid & 63;
  const int wid = tid >> 6;
  const int l15 = lane & 15, l4 = lane >> 4;
  const int wm = wid >> 1, wn = wid & 1;

  int k0 = 0;
  long long cOff = 0;
  if (zIsK) {
    k0 = blockIdx.z * Klen;
  } else {
    A += (long long)blockIdx.z * sA;
    B += (long long)blockIdx.z * sB;
    cOff = (long long)blockIdx.z * sC;
  }
  const int m0 = blockIdx.y * 64;
  const int n0 = blockIdx.x * 128;
  const bfu* Ag = A + (long long)m0 * lda + k0;
  const bfu* Bg = B + (long long)n0 * ldb + k0;

  f32x4 acc[2][4];
  const f32x4 zero = {0.f, 0.f, 0.f, 0.f};
#pragma unroll
  for (int r = 0; r < 2; ++r)
#pragma unroll
    for (int c = 0; c < 4; ++c) acc[r][c] = zero;

  const int lrow = lane >> 3;              // 0..7 sub-row within 8-row group
  const int ldst = (lane & 7) * 8;         // linear LDS dest col (16B chunks)
  const int lsrc = ldst ^ (lrow * 8);      // pre-swizzled global source col
  const int ksw = (l15 & 7) * 8;           // swizzled ds_read col offset

  const int nIter = Klen >> 6;

  auto STAGE = [&](int kt, bfu* buf) {
    const bfu* Ak = Ag + kt * 64;
    const bfu* Bk = Bg + kt * 64;
#pragma unroll
    for (int j = 0; j < 2; ++j) {
      const int row = (wid * 2 + j) * 8 + lrow;
      stage16(Ak + (long long)row * lda + lsrc, buf + row * 64 + ldst);
    }
#pragma unroll
    for (int j = 0; j < 4; ++j) {
      const int row = (wid * 4 + j) * 8 + lrow;
      stage16(Bk + (long long)row * ldb + lsrc, buf + 4096 + row * 64 + ldst);
    }
  };

  STAGE(0, S);
  asm volatile("s_waitcnt vmcnt(0)" ::: "memory");
  __builtin_amdgcn_s_barrier();

  int cur = 0;
  for (int kt = 0; kt < nIter; ++kt) {
    bfu* bufc = S + (cur ? 12288 : 0);
    bfu* bufn = S + (cur ? 0 : 12288);
    if (kt + 1 < nIter) STAGE(kt + 1, bufn);
#pragma unroll
    for (int kk = 0; kk < 2; ++kk) {
      const int ko = (kk * 32 + l4 * 8) ^ ksw;
      bf16x8 af[2], bfr[4];
#pragma unroll
      for (int r = 0; r < 2; ++r)
        af[r] = *(const bf16x8*)(bufc + (wm * 32 + r * 16 + l15) * 64 + ko);
#pragma unroll
      for (int c = 0; c < 4; ++c)
        bfr[c] = *(const bf16x8*)(bufc + 4096 + (wn * 64 + c * 16 + l15) * 64 + ko);
#pragma unroll
      for (int r = 0; r < 2; ++r)
#pragma unroll
        for (int c = 0; c < 4; ++c)
          acc[r][c] = __builtin_amdgcn_mfma_f32_16x16x32_bf16(af[r], bfr[c], acc[r][c], 0, 0, 0);
    }
    asm volatile("s_waitcnt vmcnt(0)" ::: "memory");
    __builtin_amdgcn_s_barrier();
    cur ^= 1;
  }

  if (MODE == 0) {
    float* Cf = (float*)Cv;
#pragma unroll
    for (int r = 0; r < 2; ++r) {
#pragma unroll
      for (int c = 0; c < 4; ++c) {
        const int gr = m0 + wm * 32 + r * 16 + (l4 << 2);
        const int gc = n0 + wn * 64 + c * 16 + l15;
#pragma unroll
        for (int v = 0; v < 4; ++v)
          atomicAdd(Cf + cOff + (long long)(gr + v) * ldc + gc, acc[r][c][v]);
      }
    }
  } else {
    // bf16 epilogue: repack 64x128 C tile via LDS (XOR-swizzled), 16B stores.
#pragma unroll
    for (int r = 0; r < 2; ++r) {
#pragma unroll
      for (int c = 0; c < 4; ++c) {
        const int col = wn * 64 + c * 16 + l15;
#pragma unroll
        for (int v = 0; v < 4; ++v) {
          const int row = wm * 32 + r * 16 + (l4 << 2) + v;
          S[row * 128 + (col ^ (((row >> 2) & 3) << 4))] = f2b(acc[r][c][v]);
        }
      }
    }
    __syncthreads();
    bfu* Cb = (bfu*)Cv;
#pragma unroll
    for (int i = 0; i < 4; ++i) {
      const int j = i * 256 + tid;      // 0..1023 uint4s
      const int row = j >> 4;           // 0..63
      const int colbase = (j & 15) * 8; // 0..120
      const int sc = colbase ^ (((row >> 2) & 3) << 4);
      uint4 val = *(const uint4*)(S + row * 128 + sc);
      *(uint4*)(Cb + cOff + (long long)(m0 + row) * ldc + n0 + colbase) = val;
    }
  }
}

// ---------------------------------------------------------------------------
// Final GEMM: out[8192,512] = A[8192,4096] @ B[512,4096]^T + bias.
// 64x128 tile, 1D grid of 512 blocks (2 blocks/CU), PIPE=3 counted vmcnt
// (12 loads in flight/wave), XCD chunk swizzle so each XCD owns 16 contiguous
// m-panels x all 4 n-blocks (A fetched once per XCD; kills the 2x refetch).
__global__ __launch_bounds__(256) void gemm_fin(
    const bfu* __restrict__ A, const bfu* __restrict__ B, float* __restrict__ C,
    const float* __restrict__ bias,
    int lda, int ldb, int ldc, int Klen) {
  __shared__ __align__(16) bfu S[36864];  // 3 x (At 64x64 + Bt 128x64) = 72KB
  const int tid = threadIdx.x;
  const int lane = tid & 63;
  const int wid = tid >> 6;
  const int l15 = lane & 15, l4 = lane >> 4;
  const int wm = wid >> 1, wn = wid & 1;

  // XCD swizzle: nwg=512 (%8==0, bijective), chunk=64.
  const int bid = blockIdx.x;
  const int swz = ((bid & 7) << 6) + (bid >> 3);
  const int m0 = (swz >> 2) * 64;
  const int n0 = (swz & 3) * 128;
  const bfu* Ag = A + (long long)m0 * lda;
  const bfu* Bg = B + (long long)n0 * ldb;

  f32x4 acc[2][4];
  const f32x4 zero = {0.f, 0.f, 0.f, 0.f};
#pragma unroll
  for (int r = 0; r < 2; ++r)
#pragma unroll
    for (int c = 0; c < 4; ++c) acc[r][c] = zero;

  const int lrow = lane >> 3;
  const int ldst = (lane & 7) * 8;
  const int lsrc = ldst ^ (lrow * 8);
  const int ksw = (l15 & 7) * 8;

  const int nIter = Klen >> 6;

  auto STAGE = [&](int kt, bfu* buf) {  // 6 gload_lds per lane
    const bfu* Ak = Ag + kt * 64;
    const bfu* Bk = Bg + kt * 64;
#pragma unroll
    for (int j = 0; j < 2; ++j) {
      const int row = (wid * 2 + j) * 8 + lrow;
      stage16(Ak + (long long)row * lda + lsrc, buf + row * 64 + ldst);
    }
#pragma unroll
    for (int j = 0; j < 4; ++j) {
      const int row = (wid * 4 + j) * 8 + lrow;
      stage16(Bk + (long long)row * ldb + lsrc, buf + 4096 + row * 64 + ldst);
    }
  };

  // prologue: 2 tiles in flight (12 outstanding/wave)
  STAGE(0, S);
  if (nIter > 1) STAGE(1, S + 12288);

  for (int kt = 0; kt < nIter; ++kt) {
    // all waves finished computing tile kt-1 -> its buffer ((kt+2)%3) is free
    if (kt > 0) __builtin_amdgcn_s_barrier();
    if (kt + 2 < nIter) STAGE(kt + 2, S + 12288 * ((kt + 2) % 3));
    const int rem = nIter - 1 - kt;
    if (rem >= 2)
      asm volatile("s_waitcnt vmcnt(12)" ::: "memory");  // tile kt done; kt+1,kt+2 in flight
    else if (rem == 1)
      asm volatile("s_waitcnt vmcnt(6)" ::: "memory");
    else
      asm volatile("s_waitcnt vmcnt(0)" ::: "memory");
    __builtin_amdgcn_s_barrier();

    const bfu* bufc = S + 12288 * (kt % 3);
#pragma unroll
    for (int kk = 0; kk < 2; ++kk) {
      const int ko = (kk * 32 + l4 * 8) ^ ksw;
      bf16x8 af[2], bfr[4];
#pragma unroll
      for (int r = 0; r < 2; ++r)
        af[r] = *(const bf16x8*)(bufc + (wm * 32 + r * 16 + l15) * 64 + ko);
#pragma unroll
      for (int c = 0; c < 4; ++c)
        bfr[c] = *(const bf16x8*)(bufc + 4096 + (wn * 64 + c * 16 + l15) * 64 + ko);
#pragma unroll
      for (int r = 0; r < 2; ++r)
#pragma unroll
        for (int c = 0; c < 4; ++c)
          acc[r][c] = __builtin_amdgcn_mfma_f32_16x16x32_bf16(af[r], bfr[c], acc[r][c], 0, 0, 0);
    }
  }

  // f32 + bias store (no LDS use; no trailing barrier needed)
#pragma unroll
  for (int r = 0; r < 2; ++r) {
#pragma unroll
    for (int c = 0; c < 4; ++c) {
      const int gr = m0 + wm * 32 + r * 16 + (l4 << 2);
      const int gc = n0 + wn * 64 + c * 16 + l15;
      const float bval = bias[gc];
#pragma unroll
      for (int v = 0; v < 4; ++v)
        C[(long long)(gr + v) * ldc + gc] = acc[r][c][v] + bval;
    }
  }
}

// ---------------------------------------------------------------------------
// Logits GEMM: 128x128 tile, BK=64, prefetch + swizzle, double-buffer (64KB,
// 2 blocks/CU). 1D grid 2048, XCD chunk swizzle (chunk=256) decoded y-major:
// each XCD owns 8 contiguous m-panels x all 8 heads x 4 n-blocks, so Xb is
// fetched once per XCD instead of 8x.
// Wave computes 64x64 (acc[4][4] = 32 MFMA/K-step). Stores bf16 via repack.
__global__ __launch_bounds__(256) void gemm128p(
    const bfu* __restrict__ A, const bfu* __restrict__ B, void* __restrict__ Cv,
    int lda, int ldb, int ldc,
    long long sA, long long sB, long long sC,
    int Klen) {
  __shared__ __align__(16) bfu S[32768];  // 2 x (At 128x64 + Bt 128x64) = 64KB
  const int tid = threadIdx.x;
  const int lane = tid & 63;
  const int wid = tid >> 6;
  const int l15 = lane & 15, l4 = lane >> 4;
  const int wm = wid >> 1, wn = wid & 1;

  // swizzle: nwg=2048, chunk=256; lin order y-major (y slowest, then z, x)
  const int bid = blockIdx.x;
  const int swz = ((bid & 7) << 8) + (bid >> 3);
  const int by = swz >> 5;        // 0..63  m-panel
  const int bz = (swz >> 2) & 7;  // head
  const int bx = swz & 3;         // n-block

  A += (long long)bz * sA;
  B += (long long)bz * sB;
  const long long cOff = (long long)bz * sC;
  const int m0 = by * 128;
  const int n0 = bx * 128;
  const bfu* Ag = A + (long long)m0 * lda;
  const bfu* Bg = B + (long long)n0 * ldb;

  f32x4 acc[4][4];
  const f32x4 zero = {0.f, 0.f, 0.f, 0.f};
#pragma unroll
  for (int r = 0; r < 4; ++r)
#pragma unroll
    for (int c = 0; c < 4; ++c) acc[r][c] = zero;

  const int lrow = lane >> 3;
  const int ldst = (lane & 7) * 8;
  const int lsrc = ldst ^ (lrow * 8);
  const int ksw = (l15 & 7) * 8;

  const int nIter = Klen >> 6;

  auto STAGE = [&](int kt, bfu* buf) {
    const bfu* Ak = Ag + kt * 64;
    const bfu* Bk = Bg + kt * 64;
#pragma unroll
    for (int j = 0; j < 4; ++j) {
      const int row = (wid * 4 + j) * 8 + lrow;
      stage16(Ak + (long long)row * lda + lsrc, buf + row * 64 + ldst);
    }
#pragma unroll
    for (int j = 0; j < 4; ++j) {
      const int row = (wid * 4 + j) * 8 + lrow;
      stage16(Bk + (long long)row * ldb + lsrc, buf + 8192 + row * 64 + ldst);
    }
  };

  STAGE(0, S);
  asm volatile("s_waitcnt vmcnt(0)" ::: "memory");
  __builtin_amdgcn_s_barrier();

  for (int kt = 0; kt < nIter; ++kt) {
    bfu* bufc = S + ((kt & 1) ? 16384 : 0);
    bfu* bufn = S + ((kt & 1) ? 0 : 16384);
    if (kt + 1 < nIter) STAGE(kt + 1, bufn);
#pragma unroll
    for (int kk = 0; kk < 2; ++kk) {
      const int ko = (kk * 32 + l4 * 8) ^ ksw;
      bf16x8 af[4], bfr[4];
#pragma unroll
      for (int r = 0; r < 4; ++r)
        af[r] = *(const bf16x8*)(bufc + (wm * 64 + r * 16 + l15) * 64 + ko);
#pragma unroll
      for (int c = 0; c < 4; ++c)
        bfr[c] = *(const bf16x8*)(bufc + 8192 + (wn * 64 + c * 16 + l15) * 64 + ko);
#pragma unroll
      for (int r = 0; r < 4; ++r)
#pragma unroll
        for (int c = 0; c < 4; ++c)
          acc[r][c] = __builtin_amdgcn_mfma_f32_16x16x32_bf16(af[r], bfr[c], acc[r][c], 0, 0, 0);
    }
    asm volatile("s_waitcnt vmcnt(0)" ::: "memory");
    __builtin_amdgcn_s_barrier();
  }

  // bf16 epilogue: repack 128x128 C tile via LDS (XOR-swizzled), 16B stores.
#pragma unroll
  for (int r = 0; r < 4; ++r) {
#pragma unroll
    for (int c = 0; c < 4; ++c) {
      const int col = wn * 64 + c * 16 + l15;
#pragma unroll
      for (int v = 0; v < 4; ++v) {
        const int row = wm * 64 + r * 16 + (l4 << 2) + v;
        S[row * 128 + (col ^ (((row >> 2) & 3) << 4))] = f2b(acc[r][c][v]);
      }
    }
  }
  __syncthreads();
  bfu* Cb = (bfu*)Cv;
#pragma unroll
  for (int i = 0; i < 8; ++i) {
    const int j = i * 256 + tid;      // 0..2047 uint4s
    const int row = j >> 4;           // 0..127
    const int colbase = (j & 15) * 8; // 0..120
    const int sc = colbase ^ (((row >> 2) & 3) << 4);
    uint4 val = *(const uint4*)(S + row * 128 + sc);
    *(uint4*)(Cb + cOff + (long long)(m0 + row) * ldc + n0 + colbase) = val;
  }
}

// ---------------- helpers ----------------
// fused: Xb (bf16 copy) + XTb (bf16 transpose) from one read of X.
__global__ void convT_x(const float* __restrict__ in, bfu* __restrict__ outN,
                        bfu* __restrict__ outT, int R, int C) {
  __shared__ bfu t[32][33];
  const int c0 = blockIdx.x * 32, r0 = blockIdx.y * 32;
  const int tx = threadIdx.x, ty = threadIdx.y;
  for (int i = ty; i < 32; i += 8) {
    bfu b = f2b(in[(long long)(r0 + i) * C + (c0 + tx)]);
    outN[(long long)(r0 + i) * C + (c0 + tx)] = b;
    t[i][tx] = b;
  }
  __syncthreads();
  for (int i = ty; i < 32; i += 8)
    outT[(long long)(c0 + i) * R + (r0 + tx)] = t[tx][i];
}

__global__ void transpose_k(const float* __restrict__ in, bfu* __restrict__ out,
                            int R, int C) {
  __shared__ bfu t[32][33];
  const long long boff = (long long)blockIdx.z * R * C;
  const int c0 = blockIdx.x * 32, r0 = blockIdx.y * 32;
  const int tx = threadIdx.x, ty = threadIdx.y;
  for (int i = ty; i < 32; i += 8)
    t[i][tx] = f2b(in[boff + (long long)(r0 + i) * C + (c0 + tx)]);
  __syncthreads();
  for (int i = ty; i < 32; i += 8)
    out[boff + (long long)(c0 + i) * R + (r0 + tx)] = t[tx][i];
}

__global__ __launch_bounds__(256) void conv_mat(const float* __restrict__ src,
                                                bfu* __restrict__ dst, int count4) {
  int i = blockIdx.x * 256 + threadIdx.x;
  if (i < count4) {
    float4 f = ((const float4*)src)[i];
    ushort4 o;
    o.x = f2b(f.x); o.y = f2b(f.y); o.z = f2b(f.z); o.w = f2b(f.w);
    ((ushort4*)dst)[i] = o;
  }
}

__global__ __launch_bounds__(256) void zero_k(float* __restrict__ p) {
  p[blockIdx.x * 256 + threadIdx.x] = 0.f;
}

__global__ __launch_bounds__(256) void zero_out_k(float* __restrict__ p, int n) {
  int i = blockIdx.x * 256 + threadIdx.x;
  if (i < n) p[i] = 0.f;
}

__global__ __launch_bounds__(256) void cast_kv(const float* __restrict__ K32,
                                               const float* __restrict__ V32,
                                               bfu* __restrict__ Kb, bfu* __restrict__ VTb) {
  int idx = blockIdx.x * 256 + threadIdx.x;
  int a = idx >> 9, b = idx & 511;
  Kb[idx] = f2b(K32[idx]);
  VTb[idx] = f2b(V32[b * 512 + a]);
}

__global__ __launch_bounds__(256) void cvec_k(const float* __restrict__ K32,
                                              const float* __restrict__ bq,
                                              float* __restrict__ cb) {
  const int lane = threadIdx.x & 63;
  const int w = blockIdx.x * 4 + (threadIdx.x >> 6);
  const int h = w >> 9, a = w & 511;
  float s = 0.f;
#pragma unroll
  for (int i = 0; i < 8; ++i) {
    int q = i * 64 + lane;
    s += K32[a * 512 + q] * bq[h * 512 + q];
  }
#pragma unroll
  for (int off = 32; off; off >>= 1) s += __shfl_xor(s, off, 64);
  if (lane == 0) cb[w] = s;
}

// In-place softmax over Ecat[s][h*512 .. +512], wave per row.
__global__ __launch_bounds__(256) void softmax_k(bfu* __restrict__ E, const float* __restrict__ cb) {
  const int lane = threadIdx.x & 63;
  const int w = blockIdx.x * 4 + (threadIdx.x >> 6);
  const int h = w >> 13;
  const int s = w & 8191;
  bfu* row = E + (long long)s * 4096 + h * 512;
  const float* ch = cb + h * 512 + lane * 8;
  const float scale = 0.044194173824159216f;  // 1/sqrt(512)
  union { uint4 u; bfu us[8]; } io;
  io.u = *(const uint4*)(row + lane * 8);
  float v[8];
  float m = -1e30f;
#pragma unroll
  for (int j = 0; j < 8; ++j) {
    unsigned int bi = ((unsigned int)io.us[j]) << 16;
    v[j] = (__builtin_bit_cast(float, bi) + ch[j]) * scale;
    m = fmaxf(m, v[j]);
  }
#pragma unroll
  for (int off = 32; off; off >>= 1) m = fmaxf(m, __shfl_xor(m, off, 64));
  float sum = 0.f;
#pragma unroll
  for (int j = 0; j < 8; ++j) { v[j] = __expf(v[j] - m); sum += v[j]; }
#pragma unroll
  for (int off = 32; off; off >>= 1) sum += __shfl_xor(sum, off, 64);
  const float rinv = 1.0f / sum;
#pragma unroll
  for (int j = 0; j < 8; ++j) io.us[j] = f2b(v[j] * rinv);
  *(uint4*)(row + lane * 8) = io.u;
}

extern "C" void kernel_launch(void* const* d_in, const int* in_sizes, int n_in,
                              void* d_out, int out_size, void* d_ws, size_t ws_size,
                              hipStream_t stream) {
  (void)in_sizes; (void)n_in;
  const float* X    = (const float*)d_in[0];  // [8192,512]
  const float* enc0 = (const float*)d_in[1];  // [512,8192]
  const float* enc1 = (const float*)d_in[2];  // [512,8192]
  const float* Wq   = (const float*)d_in[3];  // [8,512,512]
  const float* bq   = (const float*)d_in[4];  // [8,512]
  const float* Wc   = (const float*)d_in[5];  // [512,4096]
  const float* bc   = (const float*)d_in[6];  // [512]
  float* out = (float*)d_out;                 // [8192,512] f32

  const size_t NEED = 83902464;  // 80.02 MB
  if (ws_size < NEED) {
    zero_out_k<<<dim3((out_size + 255) / 256), 256, 0, stream>>>(out, out_size);
    return;
  }
  char* w = (char*)d_ws;
  // Ecat (64 MB, written by logits GEMM) overlays all transients below it.
  bfu*   Ecat  = (bfu*)(w + 0);           // [8192][4096] 64 MB
  bfu*   XTb   = (bfu*)(w + 0);           // [512][8192]   8 MB (transient)
  bfu*   enc0b = (bfu*)(w + 8388608);     // [512][8192]   8 MB (transient)
  bfu*   enc1b = (bfu*)(w + 16777216);    // [512][8192]   8 MB (transient)
  bfu*   WqTb  = (bfu*)(w + 25165824);    // [8][512][512] 4 MB (transient)
  bfu*   Wcb   = (bfu*)(w + 29360128);    // [512][4096]   4 MB (transient)
  float* K32   = (float*)(w + 33554432);  // [512][512]    1 MB (transient)
  float* V32   = (float*)(w + 34603008);  // [512][512]    1 MB (transient)
  bfu*   Kb    = (bfu*)(w + 35651584);    // [512][512]  0.5 MB (transient)
  bfu*   VTb   = (bfu*)(w + 36175872);    // [512][512]  0.5 MB (transient)
  bfu*   Xb    = (bfu*)(w + 67108864);    // [8192][512]   8 MB
  bfu*   Mb    = (bfu*)(w + 75497472);    // [8][512][512] 4 MB
  bfu*   Ncat  = (bfu*)(w + 79691776);    // [512][4096]   4 MB
  float* cb    = (float*)(w + 83886080);  // [8][512]     16 KB

  conv_mat<<<dim3(4096), 256, 0, stream>>>(enc0, enc0b, 1048576);
  conv_mat<<<dim3(4096), 256, 0, stream>>>(enc1, enc1b, 1048576);
  conv_mat<<<dim3(2048), 256, 0, stream>>>(Wc, Wcb, 524288);

  dim3 tb(32, 8, 1);
  // fused X convert + transpose (one read of X)
  convT_x<<<dim3(16, 256, 1), tb, 0, stream>>>(X, Xb, XTb, 8192, 512);
  transpose_k<<<dim3(16, 16, 8), tb, 0, stream>>>(Wq, WqTb, 512, 512);

  zero_k<<<dim3(2048), 256, 0, stream>>>(K32);  // K32+V32 contiguous

  // K = enc0 @ X, V = enc1 @ X  (split-K over 16 chunks of 512; 512 blocks)
  gemm64p<0><<<dim3(4, 8, 16), 256, 0, stream>>>(enc0b, XTb, K32, nullptr,
      8192, 8192, 512, 0, 0, 0, 512, 1);
  gemm64p<0><<<dim3(4, 8, 16), 256, 0, stream>>>(enc1b, XTb, V32, nullptr,
      8192, 8192, 512, 0, 0, 0, 512, 1);
  cast_kv<<<dim3(1024), 256, 0, stream>>>(K32, V32, Kb, VTb);
  cvec_k<<<dim3(1024), 256, 0, stream>>>(K32, bq, cb);

  // M_h = K @ Wq_h
  gemm64p<1><<<dim3(4, 8, 8), 256, 0, stream>>>(Kb, WqTb, Mb, nullptr,
      512, 512, 512, 0, 262144, 262144, 512, 0);
  // N_h = Wc_h @ V -> Ncat[o][h*512+a]
  gemm64p<1><<<dim3(4, 8, 8), 256, 0, stream>>>(Wcb, VTb, Ncat, nullptr,
      4096, 512, 4096, 512, 0, 512, 512, 0);

  // logits_h = X @ M_h^T -> Ecat[s][h*512+a]
  // (128x128 tile, 1D 2048 blocks, XCD-swizzled, 2 blocks/CU)
  gemm128p<<<dim3(2048), 256, 0, stream>>>(Xb, Mb, Ecat,
      512, 512, 4096, 0, 262144, 512, 512);
  softmax_k<<<dim3(16384), 256, 0, stream>>>(Ecat, cb);

  // out = Ecat @ Ncat^T + bc
  // (64x128 tile, 1D 512 blocks, XCD-swizzled, PIPE=3 counted vmcnt, 2/CU)
  gemm_fin<<<dim3(512), 256, 0, stream>>>(Ecat, Ncat, out, bc,
      4096, 4096, 512, 4096);
}

// Round 5
// 297.238 us; speedup vs baseline: 1.1079x; 1.0105x over previous
//
#include <hip/hip_runtime.h>
#include <stdint.h>

typedef unsigned short bfu;
typedef __attribute__((ext_vector_type(8))) short bf16x8;   // MFMA A/B frag
typedef __attribute__((ext_vector_type(4))) float f32x4;    // MFMA C/D frag

__device__ __forceinline__ bfu f2b(float f) {
  unsigned int i = __builtin_bit_cast(unsigned int, f);
  i += 0x7FFFu + ((i >> 16) & 1u);  // round-to-nearest-even
  return (bfu)(i >> 16);
}

// async global->LDS, 16B per lane. LDS dest must be wave-uniform base + lane*16.
__device__ __forceinline__ void stage16(const bfu* g, bfu* l) {
  __builtin_amdgcn_global_load_lds(
      (const __attribute__((address_space(1))) void*)g,
      (__attribute__((address_space(3))) void*)l, 16, 0, 0);
}

// ---------------------------------------------------------------------------
// C[M,N] = A[M,K] @ B[N,K]^T. 64x128 tile, BK=64.
// Prefetch double-buffered (one raw s_barrier + vmcnt(0) per K-step) with
// T2 XOR-swizzled LDS. 4 waves 2x2: wave computes 32x64 (acc[2][4]).
// MODE 0: atomicAdd f32 (split-K via blockIdx.z when zIsK)
// MODE 1: store bf16 via LDS repack (swizzled, 16B/lane stores)
template <int MODE>
__global__ __launch_bounds__(256) void gemm64p(
    const bfu* __restrict__ A, const bfu* __restrict__ B, void* __restrict__ Cv,
    const float* __restrict__ bias,
    int lda, int ldb, int ldc,
    long long sA, long long sB, long long sC,
    int Klen, int zIsK) {
  // two buffers of (At 64x64 = 4096) + (Bt 128x64 = 8192) = 12288 bfu (24KB)
  __shared__ __align__(16) bfu S[24576];
  const int tid = threadIdx.x;
  const int lane = tid & 63;
  const int wid = tid >> 6;
  const int l15 = lane & 15, l4 = lane >> 4;
  const int wm = wid >> 1, wn = wid & 1;

  int k0 = 0;
  long long cOff = 0;
  if (zIsK) {
    k0 = blockIdx.z * Klen;
  } else {
    A += (long long)blockIdx.z * sA;
    B += (long long)blockIdx.z * sB;
    cOff = (long long)blockIdx.z * sC;
  }
  const int m0 = blockIdx.y * 64;
  const int n0 = blockIdx.x * 128;
  const bfu* Ag = A + (long long)m0 * lda + k0;
  const bfu* Bg = B + (long long)n0 * ldb + k0;

  f32x4 acc[2][4];
  const f32x4 zero = {0.f, 0.f, 0.f, 0.f};
#pragma unroll
  for (int r = 0; r < 2; ++r)
#pragma unroll
    for (int c = 0; c < 4; ++c) acc[r][c] = zero;

  const int lrow = lane >> 3;              // 0..7 sub-row within 8-row group
  const int ldst = (lane & 7) * 8;         // linear LDS dest col (16B chunks)
  const int lsrc = ldst ^ (lrow * 8);      // pre-swizzled global source col
  const int ksw = (l15 & 7) * 8;           // swizzled ds_read col offset

  const int nIter = Klen >> 6;

  auto STAGE = [&](int kt, bfu* buf) {
    const bfu* Ak = Ag + kt * 64;
    const bfu* Bk = Bg + kt * 64;
#pragma unroll
    for (int j = 0; j < 2; ++j) {
      const int row = (wid * 2 + j) * 8 + lrow;
      stage16(Ak + (long long)row * lda + lsrc, buf + row * 64 + ldst);
    }
#pragma unroll
    for (int j = 0; j < 4; ++j) {
      const int row = (wid * 4 + j) * 8 + lrow;
      stage16(Bk + (long long)row * ldb + lsrc, buf + 4096 + row * 64 + ldst);
    }
  };

  STAGE(0, S);
  asm volatile("s_waitcnt vmcnt(0)" ::: "memory");
  __builtin_amdgcn_s_barrier();

  int cur = 0;
  for (int kt = 0; kt < nIter; ++kt) {
    bfu* bufc = S + (cur ? 12288 : 0);
    bfu* bufn = S + (cur ? 0 : 12288);
    if (kt + 1 < nIter) STAGE(kt + 1, bufn);
#pragma unroll
    for (int kk = 0; kk < 2; ++kk) {
      const int ko = (kk * 32 + l4 * 8) ^ ksw;
      bf16x8 af[2], bfr[4];
#pragma unroll
      for (int r = 0; r < 2; ++r)
        af[r] = *(const bf16x8*)(bufc + (wm * 32 + r * 16 + l15) * 64 + ko);
#pragma unroll
      for (int c = 0; c < 4; ++c)
        bfr[c] = *(const bf16x8*)(bufc + 4096 + (wn * 64 + c * 16 + l15) * 64 + ko);
#pragma unroll
      for (int r = 0; r < 2; ++r)
#pragma unroll
        for (int c = 0; c < 4; ++c)
          acc[r][c] = __builtin_amdgcn_mfma_f32_16x16x32_bf16(af[r], bfr[c], acc[r][c], 0, 0, 0);
    }
    asm volatile("s_waitcnt vmcnt(0)" ::: "memory");
    __builtin_amdgcn_s_barrier();
    cur ^= 1;
  }

  if (MODE == 0) {
    float* Cf = (float*)Cv;
#pragma unroll
    for (int r = 0; r < 2; ++r) {
#pragma unroll
      for (int c = 0; c < 4; ++c) {
        const int gr = m0 + wm * 32 + r * 16 + (l4 << 2);
        const int gc = n0 + wn * 64 + c * 16 + l15;
#pragma unroll
        for (int v = 0; v < 4; ++v)
          atomicAdd(Cf + cOff + (long long)(gr + v) * ldc + gc, acc[r][c][v]);
      }
    }
  } else {
    // bf16 epilogue: repack 64x128 C tile via LDS (XOR-swizzled), 16B stores.
#pragma unroll
    for (int r = 0; r < 2; ++r) {
#pragma unroll
      for (int c = 0; c < 4; ++c) {
        const int col = wn * 64 + c * 16 + l15;
#pragma unroll
        for (int v = 0; v < 4; ++v) {
          const int row = wm * 32 + r * 16 + (l4 << 2) + v;
          S[row * 128 + (col ^ (((row >> 2) & 3) << 4))] = f2b(acc[r][c][v]);
        }
      }
    }
    __syncthreads();
    bfu* Cb = (bfu*)Cv;
#pragma unroll
    for (int i = 0; i < 4; ++i) {
      const int j = i * 256 + tid;      // 0..1023 uint4s
      const int row = j >> 4;           // 0..63
      const int colbase = (j & 15) * 8; // 0..120
      const int sc = colbase ^ (((row >> 2) & 3) << 4);
      uint4 val = *(const uint4*)(S + row * 128 + sc);
      *(uint4*)(Cb + cOff + (long long)(m0 + row) * ldc + n0 + colbase) = val;
    }
  }
}

// ---------------------------------------------------------------------------
// Final GEMM: out[8192,512] = A[8192,4096] @ B[512,4096]^T + bias.
// 64x128 tile, 1D grid of 512 blocks (2 blocks/CU), PIPE=3 counted vmcnt,
// XCD chunk swizzle.
__global__ __launch_bounds__(256) void gemm_fin(
    const bfu* __restrict__ A, const bfu* __restrict__ B, float* __restrict__ C,
    const float* __restrict__ bias,
    int lda, int ldb, int ldc, int Klen) {
  __shared__ __align__(16) bfu S[36864];  // 3 x (At 64x64 + Bt 128x64) = 72KB
  const int tid = threadIdx.x;
  const int lane = tid & 63;
  const int wid = tid >> 6;
  const int l15 = lane & 15, l4 = lane >> 4;
  const int wm = wid >> 1, wn = wid & 1;

  // XCD swizzle: nwg=512 (%8==0, bijective), chunk=64.
  const int bid = blockIdx.x;
  const int swz = ((bid & 7) << 6) + (bid >> 3);
  const int m0 = (swz >> 2) * 64;
  const int n0 = (swz & 3) * 128;
  const bfu* Ag = A + (long long)m0 * lda;
  const bfu* Bg = B + (long long)n0 * ldb;

  f32x4 acc[2][4];
  const f32x4 zero = {0.f, 0.f, 0.f, 0.f};
#pragma unroll
  for (int r = 0; r < 2; ++r)
#pragma unroll
    for (int c = 0; c < 4; ++c) acc[r][c] = zero;

  const int lrow = lane >> 3;
  const int ldst = (lane & 7) * 8;
  const int lsrc = ldst ^ (lrow * 8);
  const int ksw = (l15 & 7) * 8;

  const int nIter = Klen >> 6;

  auto STAGE = [&](int kt, bfu* buf) {  // 6 gload_lds per lane
    const bfu* Ak = Ag + kt * 64;
    const bfu* Bk = Bg + kt * 64;
#pragma unroll
    for (int j = 0; j < 2; ++j) {
      const int row = (wid * 2 + j) * 8 + lrow;
      stage16(Ak + (long long)row * lda + lsrc, buf + row * 64 + ldst);
    }
#pragma unroll
    for (int j = 0; j < 4; ++j) {
      const int row = (wid * 4 + j) * 8 + lrow;
      stage16(Bk + (long long)row * ldb + lsrc, buf + 4096 + row * 64 + ldst);
    }
  };

  // prologue: 2 tiles in flight (12 outstanding/wave)
  STAGE(0, S);
  if (nIter > 1) STAGE(1, S + 12288);

  for (int kt = 0; kt < nIter; ++kt) {
    if (kt > 0) __builtin_amdgcn_s_barrier();
    if (kt + 2 < nIter) STAGE(kt + 2, S + 12288 * ((kt + 2) % 3));
    const int rem = nIter - 1 - kt;
    if (rem >= 2)
      asm volatile("s_waitcnt vmcnt(12)" ::: "memory");
    else if (rem == 1)
      asm volatile("s_waitcnt vmcnt(6)" ::: "memory");
    else
      asm volatile("s_waitcnt vmcnt(0)" ::: "memory");
    __builtin_amdgcn_s_barrier();

    const bfu* bufc = S + 12288 * (kt % 3);
#pragma unroll
    for (int kk = 0; kk < 2; ++kk) {
      const int ko = (kk * 32 + l4 * 8) ^ ksw;
      bf16x8 af[2], bfr[4];
#pragma unroll
      for (int r = 0; r < 2; ++r)
        af[r] = *(const bf16x8*)(bufc + (wm * 32 + r * 16 + l15) * 64 + ko);
#pragma unroll
      for (int c = 0; c < 4; ++c)
        bfr[c] = *(const bf16x8*)(bufc + 4096 + (wn * 64 + c * 16 + l15) * 64 + ko);
#pragma unroll
      for (int r = 0; r < 2; ++r)
#pragma unroll
        for (int c = 0; c < 4; ++c)
          acc[r][c] = __builtin_amdgcn_mfma_f32_16x16x32_bf16(af[r], bfr[c], acc[r][c], 0, 0, 0);
    }
  }

  // f32 + bias store (no LDS use; no trailing barrier needed)
#pragma unroll
  for (int r = 0; r < 2; ++r) {
#pragma unroll
    for (int c = 0; c < 4; ++c) {
      const int gr = m0 + wm * 32 + r * 16 + (l4 << 2);
      const int gc = n0 + wn * 64 + c * 16 + l15;
      const float bval = bias[gc];
#pragma unroll
      for (int v = 0; v < 4; ++v)
        C[(long long)(gr + v) * ldc + gc] = acc[r][c][v] + bval;
    }
  }
}

// ---------------------------------------------------------------------------
// Fused logits+softmax. Block = 64 s-rows x ONE full head (512 a-cols):
//   Ecat[s][h*512+a] = softmax_a((X[s,:] @ M_h[a,:]^T + cb[h,a]) / sqrt(512))
// 8 waves (512 thr) as 2(m) x 4(n); wave owns 32 rows x 128 cols (acc[2][8]).
// BK=64, counted-vmcnt PIPE2 (9 loads/lane/tile), both-sides LDS swizzle.
// Softmax: in-lane over 8 c-frags -> shfl_xor over 16 col-lanes -> cross-wave
// LDS reduce over the 4 n-waves. Kills the separate softmax pass (128 MB HBM).
__global__ __launch_bounds__(512) void gemm_sm(
    const bfu* __restrict__ Xb, const bfu* __restrict__ Mb,
    bfu* __restrict__ Ecat, const float* __restrict__ cb) {
  // 2 buffers x (At 64x64 = 4096 + Bt 512x64 = 32768) = 73728 bfu (144 KB)
  __shared__ __align__(16) bfu S[73728];
  const int tid = threadIdx.x;
  const int lane = tid & 63;
  const int wid = tid >> 6;              // 0..7
  const int l15 = lane & 15, l4 = lane >> 4;
  const int wm = wid >> 2, wn = wid & 3; // 2 x 4

  // XCD swizzle: nwg=1024, chunk=128; h fastest -> XCD keeps Mb panel hot.
  const int bid = blockIdx.x;
  const int swz = ((bid & 7) << 7) + (bid >> 3);
  const int h  = swz & 7;
  const int m0 = (swz >> 3) * 64;

  const bfu* Ag = Xb + (long long)m0 * 512;
  const bfu* Bg = Mb + (long long)h * 262144;

  f32x4 acc[2][8];
  const f32x4 zero = {0.f, 0.f, 0.f, 0.f};
#pragma unroll
  for (int r = 0; r < 2; ++r)
#pragma unroll
    for (int c = 0; c < 8; ++c) acc[r][c] = zero;

  const int lrow = lane >> 3;
  const int ldst = (lane & 7) * 8;
  const int lsrc = ldst ^ (lrow * 8);
  const int ksw = (l15 & 7) * 8;

  auto STAGE = [&](int kt, bfu* buf) {  // 1 A-load + 8 B-loads per lane
    const bfu* Ak = Ag + kt * 64;
    const bfu* Bk = Bg + kt * 64;
    {
      const int row = wid * 8 + lrow;   // 64 A rows
      stage16(Ak + (long long)row * 512 + lsrc, buf + row * 64 + ldst);
    }
#pragma unroll
    for (int j = 0; j < 8; ++j) {
      const int row = (wid * 8 + j) * 8 + lrow;  // 512 B rows
      stage16(Bk + (long long)row * 512 + lsrc, buf + 4096 + row * 64 + ldst);
    }
  };

  STAGE(0, S);
  for (int kt = 0; kt < 8; ++kt) {      // K = 512, BK = 64
    if (kt > 0) __builtin_amdgcn_s_barrier();
    if (kt + 1 < 8) {
      STAGE(kt + 1, S + 36864 * ((kt + 1) & 1));
      asm volatile("s_waitcnt vmcnt(9)" ::: "memory");  // tile kt done; kt+1 in flight
    } else {
      asm volatile("s_waitcnt vmcnt(0)" ::: "memory");
    }
    __builtin_amdgcn_s_barrier();

    const bfu* bufc = S + 36864 * (kt & 1);
    const bfu* Bt = bufc + 4096;
#pragma unroll
    for (int kk = 0; kk < 2; ++kk) {
      const int ko = (kk * 32 + l4 * 8) ^ ksw;
      bf16x8 af[2], bfr[8];
#pragma unroll
      for (int r = 0; r < 2; ++r)
        af[r] = *(const bf16x8*)(bufc + (wm * 32 + r * 16 + l15) * 64 + ko);
#pragma unroll
      for (int c = 0; c < 8; ++c)
        bfr[c] = *(const bf16x8*)(Bt + (wn * 128 + c * 16 + l15) * 64 + ko);
#pragma unroll
      for (int r = 0; r < 2; ++r)
#pragma unroll
        for (int c = 0; c < 8; ++c)
          acc[r][c] = __builtin_amdgcn_mfma_f32_16x16x32_bf16(af[r], bfr[c], acc[r][c], 0, 0, 0);
    }
  }
  __builtin_amdgcn_s_barrier();  // all LDS reads done before epilogue reuses S

  // ---- softmax epilogue ----
  const float scale = 0.044194173824159216f;  // 1/sqrt(512)
  float ch[8];
#pragma unroll
  for (int c = 0; c < 8; ++c) ch[c] = cb[h * 512 + wn * 128 + c * 16 + l15];
  // scaled logits in-place
#pragma unroll
  for (int r = 0; r < 2; ++r)
#pragma unroll
    for (int c = 0; c < 8; ++c)
#pragma unroll
      for (int v = 0; v < 4; ++v)
        acc[r][c][v] = (acc[r][c][v] + ch[c]) * scale;

  // per-row max: in-lane over c, then shfl over the 16 col-lanes
  float mx[2][4];
#pragma unroll
  for (int r = 0; r < 2; ++r)
#pragma unroll
    for (int v = 0; v < 4; ++v) {
      float m = acc[r][0][v];
#pragma unroll
      for (int c = 1; c < 8; ++c) m = fmaxf(m, acc[r][c][v]);
      mx[r][v] = m;
    }
#pragma unroll
  for (int off = 1; off < 16; off <<= 1)
#pragma unroll
    for (int r = 0; r < 2; ++r)
#pragma unroll
      for (int v = 0; v < 4; ++v)
        mx[r][v] = fmaxf(mx[r][v], __shfl_xor(mx[r][v], off, 64));

  // cross-wave reduce over the 4 n-waves via LDS (regions beyond repack area)
  float* redm = (float*)(S + 65536);    // [4][64]
  float* reds = (float*)(S + 66560);    // [4][64]
  if (l15 == 0) {
#pragma unroll
    for (int r = 0; r < 2; ++r)
#pragma unroll
      for (int v = 0; v < 4; ++v)
        redm[wn * 64 + wm * 32 + r * 16 + l4 * 4 + v] = mx[r][v];
  }
  __syncthreads();
  float m_[2][4];
#pragma unroll
  for (int r = 0; r < 2; ++r)
#pragma unroll
    for (int v = 0; v < 4; ++v) {
      const int row = wm * 32 + r * 16 + l4 * 4 + v;
      m_[r][v] = fmaxf(fmaxf(redm[row], redm[64 + row]),
                       fmaxf(redm[128 + row], redm[192 + row]));
    }
  // exp + row sum
  float sm[2][4];
#pragma unroll
  for (int r = 0; r < 2; ++r)
#pragma unroll
    for (int v = 0; v < 4; ++v) {
      float s = 0.f;
#pragma unroll
      for (int c = 0; c < 8; ++c) {
        acc[r][c][v] = __expf(acc[r][c][v] - m_[r][v]);
        s += acc[r][c][v];
      }
      sm[r][v] = s;
    }
#pragma unroll
  for (int off = 1; off < 16; off <<= 1)
#pragma unroll
    for (int r = 0; r < 2; ++r)
#pragma unroll
      for (int v = 0; v < 4; ++v)
        sm[r][v] += __shfl_xor(sm[r][v], off, 64);
  if (l15 == 0) {
#pragma unroll
    for (int r = 0; r < 2; ++r)
#pragma unroll
      for (int v = 0; v < 4; ++v)
        reds[wn * 64 + wm * 32 + r * 16 + l4 * 4 + v] = sm[r][v];
  }
  __syncthreads();
  float rinv[2][4];
#pragma unroll
  for (int r = 0; r < 2; ++r)
#pragma unroll
    for (int v = 0; v < 4; ++v) {
      const int row = wm * 32 + r * 16 + l4 * 4 + v;
      rinv[r][v] = 1.0f / (reds[row] + reds[64 + row] + reds[128 + row] + reds[192 + row]);
    }

  // repack 64x512 bf16 tile into S[0..32767] (l4-XOR swizzle, conflict-free)
#pragma unroll
  for (int r = 0; r < 2; ++r)
#pragma unroll
    for (int c = 0; c < 8; ++c) {
      const int col = wn * 128 + c * 16 + l15;
#pragma unroll
      for (int v = 0; v < 4; ++v) {
        const int row = wm * 32 + r * 16 + l4 * 4 + v;
        S[row * 512 + (col ^ (((row >> 2) & 3) << 4))] = f2b(acc[r][c][v] * rinv[r][v]);
      }
    }
  __syncthreads();
  // 16B coalesced stores: 64 rows x 512 cols = 4096 chunks / 512 thr = 8 iters
#pragma unroll
  for (int i = 0; i < 8; ++i) {
    const int j = i * 512 + tid;
    const int row = j >> 6;            // 0..63
    const int colb = (j & 63) * 8;     // 0..504
    const int sc = colb ^ (((row >> 2) & 3) << 4);
    uint4 val = *(const uint4*)(S + row * 512 + sc);
    *(uint4*)(Ecat + (long long)(m0 + row) * 4096 + h * 512 + colb) = val;
  }
}

// ---------------- helpers ----------------
// fused: Xb (bf16 copy) + XTb (bf16 transpose) from one read of X.
__global__ void convT_x(const float* __restrict__ in, bfu* __restrict__ outN,
                        bfu* __restrict__ outT, int R, int C) {
  __shared__ bfu t[32][33];
  const int c0 = blockIdx.x * 32, r0 = blockIdx.y * 32;
  const int tx = threadIdx.x, ty = threadIdx.y;
  for (int i = ty; i < 32; i += 8) {
    bfu b = f2b(in[(long long)(r0 + i) * C + (c0 + tx)]);
    outN[(long long)(r0 + i) * C + (c0 + tx)] = b;
    t[i][tx] = b;
  }
  __syncthreads();
  for (int i = ty; i < 32; i += 8)
    outT[(long long)(c0 + i) * R + (r0 + tx)] = t[tx][i];
}

__global__ void transpose_k(const float* __restrict__ in, bfu* __restrict__ out,
                            int R, int C) {
  __shared__ bfu t[32][33];
  const long long boff = (long long)blockIdx.z * R * C;
  const int c0 = blockIdx.x * 32, r0 = blockIdx.y * 32;
  const int tx = threadIdx.x, ty = threadIdx.y;
  for (int i = ty; i < 32; i += 8)
    t[i][tx] = f2b(in[boff + (long long)(r0 + i) * C + (c0 + tx)]);
  __syncthreads();
  for (int i = ty; i < 32; i += 8)
    out[boff + (long long)(c0 + i) * R + (r0 + tx)] = t[tx][i];
}

__global__ __launch_bounds__(256) void conv_mat(const float* __restrict__ src,
                                                bfu* __restrict__ dst, int count4) {
  int i = blockIdx.x * 256 + threadIdx.x;
  if (i < count4) {
    float4 f = ((const float4*)src)[i];
    ushort4 o;
    o.x = f2b(f.x); o.y = f2b(f.y); o.z = f2b(f.z); o.w = f2b(f.w);
    ((ushort4*)dst)[i] = o;
  }
}

__global__ __launch_bounds__(256) void zero_k(float* __restrict__ p) {
  p[blockIdx.x * 256 + threadIdx.x] = 0.f;
}

__global__ __launch_bounds__(256) void zero_out_k(float* __restrict__ p, int n) {
  int i = blockIdx.x * 256 + threadIdx.x;
  if (i < n) p[i] = 0.f;
}

__global__ __launch_bounds__(256) void cast_kv(const float* __restrict__ K32,
                                               const float* __restrict__ V32,
                                               bfu* __restrict__ Kb, bfu* __restrict__ VTb) {
  int idx = blockIdx.x * 256 + threadIdx.x;
  int a = idx >> 9, b = idx & 511;
  Kb[idx] = f2b(K32[idx]);
  VTb[idx] = f2b(V32[b * 512 + a]);
}

__global__ __launch_bounds__(256) void cvec_k(const float* __restrict__ K32,
                                              const float* __restrict__ bq,
                                              float* __restrict__ cb) {
  const int lane = threadIdx.x & 63;
  const int w = blockIdx.x * 4 + (threadIdx.x >> 6);
  const int h = w >> 9, a = w & 511;
  float s = 0.f;
#pragma unroll
  for (int i = 0; i < 8; ++i) {
    int q = i * 64 + lane;
    s += K32[a * 512 + q] * bq[h * 512 + q];
  }
#pragma unroll
  for (int off = 32; off; off >>= 1) s += __shfl_xor(s, off, 64);
  if (lane == 0) cb[w] = s;
}

extern "C" void kernel_launch(void* const* d_in, const int* in_sizes, int n_in,
                              void* d_out, int out_size, void* d_ws, size_t ws_size,
                              hipStream_t stream) {
  (void)in_sizes; (void)n_in;
  const float* X    = (const float*)d_in[0];  // [8192,512]
  const float* enc0 = (const float*)d_in[1];  // [512,8192]
  const float* enc1 = (const float*)d_in[2];  // [512,8192]
  const float* Wq   = (const float*)d_in[3];  // [8,512,512]
  const float* bq   = (const float*)d_in[4];  // [8,512]
  const float* Wc   = (const float*)d_in[5];  // [512,4096]
  const float* bc   = (const float*)d_in[6];  // [512]
  float* out = (float*)d_out;                 // [8192,512] f32

  const size_t NEED = 83902464;  // 80.02 MB
  if (ws_size < NEED) {
    zero_out_k<<<dim3((out_size + 255) / 256), 256, 0, stream>>>(out, out_size);
    return;
  }
  char* w = (char*)d_ws;
  // Ecat (64 MB, written by gemm_sm) overlays all transients below it.
  bfu*   Ecat  = (bfu*)(w + 0);           // [8192][4096] 64 MB
  bfu*   XTb   = (bfu*)(w + 0);           // [512][8192]   8 MB (transient)
  bfu*   enc0b = (bfu*)(w + 8388608);     // [512][8192]   8 MB (transient)
  bfu*   enc1b = (bfu*)(w + 16777216);    // [512][8192]   8 MB (transient)
  bfu*   WqTb  = (bfu*)(w + 25165824);    // [8][512][512] 4 MB (transient)
  bfu*   Wcb   = (bfu*)(w + 29360128);    // [512][4096]   4 MB (transient)
  float* K32   = (float*)(w + 33554432);  // [512][512]    1 MB (transient)
  float* V32   = (float*)(w + 34603008);  // [512][512]    1 MB (transient)
  bfu*   Kb    = (bfu*)(w + 35651584);    // [512][512]  0.5 MB (transient)
  bfu*   VTb   = (bfu*)(w + 36175872);    // [512][512]  0.5 MB (transient)
  bfu*   Xb    = (bfu*)(w + 67108864);    // [8192][512]   8 MB
  bfu*   Mb    = (bfu*)(w + 75497472);    // [8][512][512] 4 MB
  bfu*   Ncat  = (bfu*)(w + 79691776);    // [512][4096]   4 MB
  float* cb    = (float*)(w + 83886080);  // [8][512]     16 KB

  conv_mat<<<dim3(4096), 256, 0, stream>>>(enc0, enc0b, 1048576);
  conv_mat<<<dim3(4096), 256, 0, stream>>>(enc1, enc1b, 1048576);
  conv_mat<<<dim3(2048), 256, 0, stream>>>(Wc, Wcb, 524288);

  dim3 tb(32, 8, 1);
  // fused X convert + transpose (one read of X)
  convT_x<<<dim3(16, 256, 1), tb, 0, stream>>>(X, Xb, XTb, 8192, 512);
  transpose_k<<<dim3(16, 16, 8), tb, 0, stream>>>(Wq, WqTb, 512, 512);

  zero_k<<<dim3(2048), 256, 0, stream>>>(K32);  // K32+V32 contiguous

  // K = enc0 @ X, V = enc1 @ X  (split-K over 16 chunks of 512; 512 blocks)
  gemm64p<0><<<dim3(4, 8, 16), 256, 0, stream>>>(enc0b, XTb, K32, nullptr,
      8192, 8192, 512, 0, 0, 0, 512, 1);
  gemm64p<0><<<dim3(4, 8, 16), 256, 0, stream>>>(enc1b, XTb, V32, nullptr,
      8192, 8192, 512, 0, 0, 0, 512, 1);
  cast_kv<<<dim3(1024), 256, 0, stream>>>(K32, V32, Kb, VTb);
  cvec_k<<<dim3(1024), 256, 0, stream>>>(K32, bq, cb);

  // M_h = K @ Wq_h
  gemm64p<1><<<dim3(4, 8, 8), 256, 0, stream>>>(Kb, WqTb, Mb, nullptr,
      512, 512, 512, 0, 262144, 262144, 512, 0);
  // N_h = Wc_h @ V -> Ncat[o][h*512+a]
  gemm64p<1><<<dim3(4, 8, 8), 256, 0, stream>>>(Wcb, VTb, Ncat, nullptr,
      4096, 512, 4096, 512, 0, 512, 512, 0);

  // fused logits+softmax -> Ecat (1024 blocks, 512 thr, XCD-swizzled)
  gemm_sm<<<dim3(1024), 512, 0, stream>>>(Xb, Mb, Ecat, cb);

  // out = Ecat @ Ncat^T + bc
  // (64x128 tile, 1D 512 blocks, XCD-swizzled, PIPE=3 counted vmcnt, 2/CU)
  gemm_fin<<<dim3(512), 256, 0, stream>>>(Ecat, Ncat, out, bc,
      4096, 4096, 512, 4096);
}